// Round 7
// baseline (559.254 us; speedup 1.0000x reference)
//
#include <hip/hip_runtime.h>
#include <hip/hip_bf16.h>
#include <math.h>

#define S_LEN 2048
#define D_MODEL 1024
#define N_BATCH 4
#define N_HALF 512

typedef unsigned short u16;
typedef __attribute__((ext_vector_type(8))) short bf16x8;
typedef __attribute__((ext_vector_type(4))) float f32x4;

// ---------- helpers ----------
__device__ inline u16 f2bf(float v) {
  __hip_bfloat16 h = __float2bfloat16(v);   // RNE
  return *reinterpret_cast<u16*>(&h);
}
__device__ inline float bf2f(u16 u) {
  __hip_bfloat16 h = *reinterpret_cast<__hip_bfloat16*>(&u);
  return __bfloat162float(h);
}
// async global->LDS, 16B per lane; LDS dest is wave-uniform base + lane*16
__device__ inline void gl2lds16(const void* g, void* l) {
  __builtin_amdgcn_global_load_lds(
      (const __attribute__((address_space(1))) unsigned int*)g,
      (__attribute__((address_space(3))) unsigned int*)l, 16, 0, 0);
}
// tanh via v_exp_f32; exact at 0, saturates correctly at +/-inf (no NaN)
__device__ inline float fast_tanh(float x) {
  float e = __expf(2.0f * x);
  return 1.0f - 2.0f / (e + 1.0f);
}

// ---------- casts ----------
__global__ __launch_bounds__(256)
void cast_bf(const float* __restrict__ src, u16* __restrict__ dst, long long n) {
  long long i = (long long)blockIdx.x * 256 + threadIdx.x;
  if (i < n) dst[i] = f2bf(src[i]);
}
__global__ __launch_bounds__(256)
void cast_split(const float* __restrict__ src, u16* __restrict__ hi,
                u16* __restrict__ lo, long long n) {
  long long i = (long long)blockIdx.x * 256 + threadIdx.x;
  if (i < n) {
    float v = src[i];
    u16 h = f2bf(v);
    hi[i] = h;
    lo[i] = f2bf(v - bf2f(h));
  }
}
__global__ __launch_bounds__(256)
void zero_stats(float* __restrict__ p, int n) {
  int i = blockIdx.x * 256 + threadIdx.x;
  if (i < n) p[i] = 0.f;
}

// ============================================================
// MFMA GEMM (NT): C[M,N] = A[M,K] * B[N,K]^T + bias[col], bf16 out.
// 128x128 tile, 256 thr (4 waves, 2x2 of 64x64), BK=32,
// global_load_lds width16, LDS row-major [128][32]. ld == K for A and B.
// bias selected per z from {b0,b1,b2} (z>=2 -> b2).
// ============================================================
__global__ __launch_bounds__(256)
void mfma_gemm_bias(const u16* __restrict__ A, const u16* __restrict__ B,
                    const float* __restrict__ b0, const float* __restrict__ b1,
                    const float* __restrict__ b2,
                    u16* __restrict__ C,
                    int N, int K,
                    long long sA, long long sB, long long sC) {
  __shared__ u16 As[128 * 32];
  __shared__ u16 Bs[128 * 32];
  const int tid  = threadIdx.x;
  const int wave = tid >> 6;
  const int lane = tid & 63;
  const int quad = lane >> 4;
  const int tc   = lane & 15;
  const int bm = blockIdx.y * 128;
  const int bn = blockIdx.x * 128;
  const long long z = blockIdx.z;
  const float* bias = (z == 0) ? b0 : (z == 1) ? b1 : b2;

  const int wm = (wave & 1) * 64;
  const int wn = (wave >> 1) * 64;

  f32x4 acc[4][4];
#pragma unroll
  for (int i = 0; i < 4; i++)
#pragma unroll
    for (int j = 0; j < 4; j++) acc[i][j] = (f32x4){0.f, 0.f, 0.f, 0.f};

  const int srow = wave * 32 + (lane >> 2);
  const int scol = (lane & 3) * 8;
  const u16* ga = A + z * sA + (long long)(bm + srow) * K + scol;
  const u16* gb = B + z * sB + (long long)(bn + srow) * K + scol;
  u16* lA0 = As + (wave * 32) * 32;
  u16* lB0 = Bs + (wave * 32) * 32;
  const long long r16K = 16LL * K;

  for (int k0 = 0; k0 < K; k0 += 32) {
    gl2lds16(ga,        lA0);
    gl2lds16(ga + r16K, lA0 + 512);
    gl2lds16(gb,        lB0);
    gl2lds16(gb + r16K, lB0 + 512);
    ga += 32; gb += 32;
    __syncthreads();
    bf16x8 af[4], bg[4];
#pragma unroll
    for (int i = 0; i < 4; i++)
      af[i] = *(const bf16x8*)(As + (wm + i * 16 + tc) * 32 + quad * 8);
#pragma unroll
    for (int j = 0; j < 4; j++)
      bg[j] = *(const bf16x8*)(Bs + (wn + j * 16 + tc) * 32 + quad * 8);
#pragma unroll
    for (int i = 0; i < 4; i++)
#pragma unroll
      for (int j = 0; j < 4; j++)
        acc[i][j] = __builtin_amdgcn_mfma_f32_16x16x32_bf16(af[i], bg[j], acc[i][j], 0, 0, 0);
    __syncthreads();
  }

  u16* Cz = C + z * sC;
#pragma unroll
  for (int i = 0; i < 4; i++) {
    const int row0 = bm + wm + i * 16 + quad * 4;
#pragma unroll
    for (int j = 0; j < 4; j++) {
      const int col = bn + wn + j * 16 + tc;
#pragma unroll
      for (int r = 0; r < 4; r++)
        Cz[(long long)(row0 + r) * N + col] = f2bf(acc[i][j][r] + bias[col]);
    }
  }
}

// ============================================================
// A-split GEMM (VWt): C = (Ah+Al) @ B^T, hi/lo bf16 out, no bias.
// A = split(Wo) [D,D] (no batch); B = V_b [S,D] per z; C[d][s] per z.
// ============================================================
__global__ __launch_bounds__(256)
void gemm_asplit(const u16* __restrict__ Ah, const u16* __restrict__ Al,
                 const u16* __restrict__ B,
                 u16* __restrict__ Ch, u16* __restrict__ Cl,
                 int N, int K, long long sB, long long sC) {
  __shared__ u16 Ash[128 * 32];
  __shared__ u16 Asl[128 * 32];
  __shared__ u16 Bs[128 * 32];
  const int tid  = threadIdx.x;
  const int wave = tid >> 6;
  const int lane = tid & 63;
  const int quad = lane >> 4;
  const int tc   = lane & 15;
  const int bm = blockIdx.y * 128;
  const int bn = blockIdx.x * 128;
  const long long z = blockIdx.z;
  const int wm = (wave & 1) * 64;
  const int wn = (wave >> 1) * 64;

  f32x4 acc[4][4];
#pragma unroll
  for (int i = 0; i < 4; i++)
#pragma unroll
    for (int j = 0; j < 4; j++) acc[i][j] = (f32x4){0.f, 0.f, 0.f, 0.f};

  const int srow = wave * 32 + (lane >> 2);
  const int scol = (lane & 3) * 8;
  const long long aoff = (long long)(bm + srow) * K + scol;
  const u16* gah = Ah + aoff;
  const u16* gal = Al + aoff;
  const u16* gb  = B + z * sB + (long long)(bn + srow) * K + scol;
  const int wb = (wave * 32) * 32;
  const long long r16K = 16LL * K;

  for (int k0 = 0; k0 < K; k0 += 32) {
    gl2lds16(gah,        Ash + wb);
    gl2lds16(gah + r16K, Ash + wb + 512);
    gl2lds16(gal,        Asl + wb);
    gl2lds16(gal + r16K, Asl + wb + 512);
    gl2lds16(gb,         Bs + wb);
    gl2lds16(gb + r16K,  Bs + wb + 512);
    gah += 32; gal += 32; gb += 32;
    __syncthreads();
    bf16x8 ah[4], al[4], bg[4];
#pragma unroll
    for (int i = 0; i < 4; i++) {
      int o = (wm + i * 16 + tc) * 32 + quad * 8;
      ah[i] = *(const bf16x8*)(Ash + o);
      al[i] = *(const bf16x8*)(Asl + o);
    }
#pragma unroll
    for (int j = 0; j < 4; j++)
      bg[j] = *(const bf16x8*)(Bs + (wn + j * 16 + tc) * 32 + quad * 8);
#pragma unroll
    for (int i = 0; i < 4; i++)
#pragma unroll
      for (int j = 0; j < 4; j++) {
        acc[i][j] = __builtin_amdgcn_mfma_f32_16x16x32_bf16(ah[i], bg[j], acc[i][j], 0, 0, 0);
        acc[i][j] = __builtin_amdgcn_mfma_f32_16x16x32_bf16(al[i], bg[j], acc[i][j], 0, 0, 0);
      }
    __syncthreads();
  }

  u16* Chz = Ch + z * sC;
  u16* Clz = Cl + z * sC;
#pragma unroll
  for (int i = 0; i < 4; i++) {
    const int row0 = bm + wm + i * 16 + quad * 4;
#pragma unroll
    for (int j = 0; j < 4; j++) {
      const int col = bn + wn + j * 16 + tc;
#pragma unroll
      for (int r = 0; r < 4; r++) {
        float v = acc[i][j][r];
        long long idx = (long long)(row0 + r) * N + col;
        u16 h = f2bf(v);
        Chz[idx] = h;
        Clz[idx] = f2bf(v - bf2f(h));
      }
    }
  }
}

// ============================================================
// B-split GEMM (out): C = A @ (Bh+Bl)^T + bias[col], fp32 out.
// A = attn_b [S,S]; B = split(VWt_b) [D rows, ld=S]; C = out rows per z.
// ============================================================
__global__ __launch_bounds__(256)
void gemm_bsplit(const u16* __restrict__ A,
                 const u16* __restrict__ Bh, const u16* __restrict__ Bl,
                 const float* __restrict__ bias, float* __restrict__ C,
                 int N, int K, long long sA, long long sB, long long sC) {
  __shared__ u16 As[128 * 32];
  __shared__ u16 Bsh[128 * 32];
  __shared__ u16 Bsl[128 * 32];
  const int tid  = threadIdx.x;
  const int wave = tid >> 6;
  const int lane = tid & 63;
  const int quad = lane >> 4;
  const int tc   = lane & 15;
  const int bm = blockIdx.y * 128;
  const int bn = blockIdx.x * 128;
  const long long z = blockIdx.z;
  const int wm = (wave & 1) * 64;
  const int wn = (wave >> 1) * 64;

  f32x4 acc[4][4];
#pragma unroll
  for (int i = 0; i < 4; i++)
#pragma unroll
    for (int j = 0; j < 4; j++) acc[i][j] = (f32x4){0.f, 0.f, 0.f, 0.f};

  const int srow = wave * 32 + (lane >> 2);
  const int scol = (lane & 3) * 8;
  const long long boff = (long long)(bn + srow) * K + scol;
  const u16* ga  = A + z * sA + (long long)(bm + srow) * K + scol;
  const u16* gbh = Bh + z * sB + boff;
  const u16* gbl = Bl + z * sB + boff;
  const int wb = (wave * 32) * 32;
  const long long r16K = 16LL * K;

  for (int k0 = 0; k0 < K; k0 += 32) {
    gl2lds16(ga,         As + wb);
    gl2lds16(ga + r16K,  As + wb + 512);
    gl2lds16(gbh,        Bsh + wb);
    gl2lds16(gbh + r16K, Bsh + wb + 512);
    gl2lds16(gbl,        Bsl + wb);
    gl2lds16(gbl + r16K, Bsl + wb + 512);
    ga += 32; gbh += 32; gbl += 32;
    __syncthreads();
    bf16x8 af[4], bh[4], bl[4];
#pragma unroll
    for (int i = 0; i < 4; i++)
      af[i] = *(const bf16x8*)(As + (wm + i * 16 + tc) * 32 + quad * 8);
#pragma unroll
    for (int j = 0; j < 4; j++) {
      int o = (wn + j * 16 + tc) * 32 + quad * 8;
      bh[j] = *(const bf16x8*)(Bsh + o);
      bl[j] = *(const bf16x8*)(Bsl + o);
    }
#pragma unroll
    for (int i = 0; i < 4; i++)
#pragma unroll
      for (int j = 0; j < 4; j++) {
        acc[i][j] = __builtin_amdgcn_mfma_f32_16x16x32_bf16(af[i], bh[j], acc[i][j], 0, 0, 0);
        acc[i][j] = __builtin_amdgcn_mfma_f32_16x16x32_bf16(af[i], bl[j], acc[i][j], 0, 0, 0);
      }
    __syncthreads();
  }

  float* Cz = C + z * sC;
#pragma unroll
  for (int i = 0; i < 4; i++) {
    const int row0 = bm + wm + i * 16 + quad * 4;
#pragma unroll
    for (int j = 0; j < 4; j++) {
      const int col = bn + wn + j * 16 + tc;
#pragma unroll
      for (int r = 0; r < 4; r++)
        Cz[(long long)(row0 + r) * N + col] = acc[i][j][r] + bias[col];
    }
  }
}

// ============================================================
// Fused chaotic kernel (validated round-6 body, unchanged).
// ============================================================
__global__ __launch_bounds__(256, 2)
void chaotic_fused(const u16* __restrict__ Q, const u16* __restrict__ Kt,
                   const u16* __restrict__ Uq, const u16* __restrict__ Uk,
                   float* __restrict__ Cc,
                   float* __restrict__ ssum, float* __restrict__ ssq,
                   const float* __restrict__ bifp, const float* __restrict__ pcp) {
  __shared__ u16 Qs[128 * 32];
  __shared__ u16 Ks[128 * 32];
  __shared__ u16 Us[128 * 32];
  __shared__ u16 Ws[128 * 32];
  const int tid  = threadIdx.x;
  const int wave = tid >> 6;
  const int lane = tid & 63;
  const int quad = lane >> 4;
  const int tc   = lane & 15;
  const int bm = blockIdx.y * 128;
  const int bn = blockIdx.x * 128;
  const long long z = blockIdx.z;
  const long long sQ = (long long)S_LEN * D_MODEL;
  const int wm = (wave & 1) * 64;
  const int wn = (wave >> 1) * 64;

  f32x4 acc1[4][4], acc2[4][4];
#pragma unroll
  for (int i = 0; i < 4; i++)
#pragma unroll
    for (int j = 0; j < 4; j++) {
      acc1[i][j] = (f32x4){0.f, 0.f, 0.f, 0.f};
      acc2[i][j] = (f32x4){0.f, 0.f, 0.f, 0.f};
    }

  const int srow = wave * 32 + (lane >> 2);
  const int scol = (lane & 3) * 8;
  const long long aoff = (long long)(bm + srow) * D_MODEL + scol;
  const long long boff = (long long)(bn + srow) * D_MODEL + scol;
  const u16* gq = Q  + z * sQ + aoff;
  const u16* gk = Kt + z * sQ + boff;
  const u16* gu = Uq + z * sQ + aoff;
  const u16* gw = Uk + z * sQ + boff;
  const int wb = (wave * 32) * 32;
  const long long r16 = 16LL * D_MODEL;

  for (int k0 = 0; k0 < D_MODEL; k0 += 32) {
    gl2lds16(gq,       Qs + wb);
    gl2lds16(gq + r16, Qs + wb + 512);
    gl2lds16(gk,       Ks + wb);
    gl2lds16(gk + r16, Ks + wb + 512);
    gl2lds16(gu,       Us + wb);
    gl2lds16(gu + r16, Us + wb + 512);
    gl2lds16(gw,       Ws + wb);
    gl2lds16(gw + r16, Ws + wb + 512);
    gq += 32; gk += 32; gu += 32; gw += 32;
    __syncthreads();
    {
      bf16x8 af[4], bg[4];
#pragma unroll
      for (int i = 0; i < 4; i++)
        af[i] = *(const bf16x8*)(Qs + (wm + i * 16 + tc) * 32 + quad * 8);
#pragma unroll
      for (int j = 0; j < 4; j++)
        bg[j] = *(const bf16x8*)(Ks + (wn + j * 16 + tc) * 32 + quad * 8);
#pragma unroll
      for (int i = 0; i < 4; i++)
#pragma unroll
        for (int j = 0; j < 4; j++)
          acc1[i][j] = __builtin_amdgcn_mfma_f32_16x16x32_bf16(af[i], bg[j], acc1[i][j], 0, 0, 0);
    }
    {
      bf16x8 cf[4], dg[4];
#pragma unroll
      for (int i = 0; i < 4; i++)
        cf[i] = *(const bf16x8*)(Us + (wm + i * 16 + tc) * 32 + quad * 8);
#pragma unroll
      for (int j = 0; j < 4; j++)
        dg[j] = *(const bf16x8*)(Ws + (wn + j * 16 + tc) * 32 + quad * 8);
#pragma unroll
      for (int i = 0; i < 4; i++)
#pragma unroll
        for (int j = 0; j < 4; j++)
          acc2[i][j] = __builtin_amdgcn_mfma_f32_16x16x32_bf16(cf[i], dg[j], acc2[i][j], 0, 0, 0);
    }
    __syncthreads();
  }

  const float bif = *bifp;
  const float pc  = *pcp;
  float rsum[4][4], rsq[4][4];
#pragma unroll
  for (int i = 0; i < 4; i++)
#pragma unroll
    for (int r = 0; r < 4; r++) { rsum[i][r] = 0.f; rsq[i][r] = 0.f; }

  float* C = Cc + z * (long long)S_LEN * S_LEN;
#pragma unroll
  for (int i = 0; i < 4; i++) {
    const int row0 = bm + wm + i * 16 + quad * 4;
#pragma unroll
    for (int j = 0; j < 4; j++) {
      const int col = bn + wn + j * 16 + tc;
#pragma unroll
      for (int r = 0; r < 4; r++) {
        float sc = acc1[i][j][r] * 0.03125f;          // / sqrt(1024)
        float sy = acc2[i][j][r] * (1.0f / 512.0f);   // / HALF
        float t  = fast_tanh(sc);
        C[(long long)(row0 + r) * S_LEN + col] = sc + pc * sy + bif * t * (1.0f - t);
        rsum[i][r] += sy;
        rsq[i][r]  += sy * sy;
      }
    }
  }
#pragma unroll
  for (int m = 1; m < 16; m <<= 1) {
#pragma unroll
    for (int i = 0; i < 4; i++)
#pragma unroll
      for (int r = 0; r < 4; r++) {
        rsum[i][r] += __shfl_xor(rsum[i][r], m);
        rsq[i][r]  += __shfl_xor(rsq[i][r], m);
      }
  }
  if (tc == 0) {
#pragma unroll
    for (int i = 0; i < 4; i++)
#pragma unroll
      for (int r = 0; r < 4; r++) {
        long long rr = z * S_LEN + bm + wm + i * 16 + quad * 4 + r;
        atomicAdd(&ssum[rr], rsum[i][r]);
        atomicAdd(&ssq[rr],  rsq[i][r]);
      }
  }
}

// ============================================================
// Phase normalize in place on dense bf16 pf rows (stride 1024)
// ============================================================
__global__ __launch_bounds__(256)
void phase_norm_bf(u16* __restrict__ U, long long n_rows) {
  long long idx = (long long)blockIdx.x * 256 + threadIdx.x;
  if (idx >= n_rows * N_HALF) return;
  long long row = idx >> 9;
  int j = (int)(idx & (N_HALF - 1));
  u16* p = U + row * D_MODEL;
  float re = bf2f(p[j]), im = bf2f(p[j + N_HALF]);
  float n2 = re * re + im * im;
  float cr = 1.f, sr = 0.f;
  if (n2 > 0.f) {
    float inv = 1.0f / sqrtf(n2);
    cr = re * inv; sr = im * inv;
  }
  p[j] = f2bf(cr); p[j + N_HALF] = f2bf(sr);
}

// ============================================================
// Row softmax: fp32 in (chaotic), bf16 out (attn). 1 block / row.
// ============================================================
__global__ __launch_bounds__(256)
void softmax_bf(const float* __restrict__ Cc, u16* __restrict__ P) {
  const long long row = (long long)blockIdx.y * S_LEN + blockIdx.x;
  const float* p = Cc + row * S_LEN;
  u16* q = P + row * S_LEN;
  const int tid = threadIdx.x;
  float v[8];
  float m = -3.402823466e+38f;
#pragma unroll
  for (int i = 0; i < 8; i++) { v[i] = p[tid + i * 256]; m = fmaxf(m, v[i]); }
#pragma unroll
  for (int mask = 1; mask < 64; mask <<= 1) m = fmaxf(m, __shfl_xor(m, mask));
  __shared__ float red[8];
  if ((tid & 63) == 0) red[tid >> 6] = m;
  __syncthreads();
  m = fmaxf(fmaxf(red[0], red[1]), fmaxf(red[2], red[3]));
  float s = 0.f;
#pragma unroll
  for (int i = 0; i < 8; i++) { v[i] = __expf(v[i] - m); s += v[i]; }
#pragma unroll
  for (int mask = 1; mask < 64; mask <<= 1) s += __shfl_xor(s, mask);
  __syncthreads();
  if ((tid & 63) == 0) red[4 + (tid >> 6)] = s;
  __syncthreads();
  s = red[4] + red[5] + red[6] + red[7];
  float inv = 1.0f / s;
#pragma unroll
  for (int i = 0; i < 8; i++) q[tid + i * 256] = f2bf(v[i] * inv);
}

// ============================================================
// sync_loss
// ============================================================
__global__ __launch_bounds__(1024)
void syncloss_kernel(const float* __restrict__ ssum, const float* __restrict__ ssq,
                     float* __restrict__ out) {
  const int tid = threadIdx.x;
  float acc = 0.f;
  for (int r = tid; r < N_BATCH * S_LEN; r += 1024) {
    float su = ssum[r], sq = ssq[r];
    acc += (sq - su * su * (1.0f / 2048.0f)) * (1.0f / 2047.0f);
  }
#pragma unroll
  for (int mask = 1; mask < 64; mask <<= 1) acc += __shfl_xor(acc, mask);
  __shared__ float red[16];
  if ((tid & 63) == 0) red[tid >> 6] = acc;
  __syncthreads();
  if (tid == 0) {
    float t = 0.f;
#pragma unroll
    for (int k = 0; k < 16; k++) t += red[k];
    out[0] = 0.01f * (t / (float)(N_BATCH * S_LEN));
  }
}

extern "C" void kernel_launch(void* const* d_in, const int* in_sizes, int n_in,
                              void* d_out, int out_size, void* d_ws, size_t ws_size,
                              hipStream_t stream) {
  const float* x    = (const float*)d_in[0];
  const float* Wq   = (const float*)d_in[1];
  const float* bq   = (const float*)d_in[2];
  const float* Wk   = (const float*)d_in[3];
  const float* bk   = (const float*)d_in[4];
  const float* Wv   = (const float*)d_in[5];
  const float* bv   = (const float*)d_in[6];
  const float* Wp   = (const float*)d_in[7];
  const float* bp   = (const float*)d_in[8];
  const float* Wo   = (const float*)d_in[9];
  const float* bo   = (const float*)d_in[10];
  const float* bifp = (const float*)d_in[11];
  const float* pcp  = (const float*)d_in[12];
  float* out = (float*)d_out;

  const long long NROW = (long long)N_BATCH * S_LEN;   // 8192
  const long long TD   = NROW * D_MODEL;               // 8,388,608
  const long long WSZ  = (long long)D_MODEL * D_MODEL; // 1,048,576

  // workspace layout (~178 MB)
  u16* xbf   = (u16*)d_ws;          // TD
  u16* wqkvb = xbf + TD;            // 3*WSZ (Wq, Wk, Wv contiguous)
  u16* wpb   = wqkvb + 3 * WSZ;     // WSZ
  u16* woh   = wpb + WSZ;           // WSZ (Wo hi)
  u16* wol   = woh + WSZ;           // WSZ (Wo lo)
  u16* Qbf   = wol + WSZ;           // TD
  u16* Kbf   = Qbf + TD;            // TD
  u16* Vbf   = Kbf + TD;            // TD ([b][s][d], natural layout)
  u16* pfQ   = Vbf + TD;            // TD (-> Uq; later VWt hi)
  u16* pfK   = pfQ + TD;            // TD (-> Uk; later VWt lo)
  float* Cc  = (float*)(pfK + TD);  // B*S*S fp32
  float* ssum = Cc + (long long)N_BATCH * S_LEN * S_LEN;
  float* ssq  = ssum + NROW;
  u16* attn = Qbf;                  // overlays Q+K after chaotic (2*TD)
  u16* vwh  = pfQ;                  // overlays Uq after chaotic
  u16* vwl  = pfK;                  // overlays Uk after chaotic

  dim3 blk(256);
  const long long sQ = (long long)S_LEN * D_MODEL;   // 2048*1024
  const long long sS = (long long)S_LEN * S_LEN;

  // casts
  cast_bf<<<(int)(TD / 256), blk, 0, stream>>>(x, xbf, TD);
  cast_bf<<<(int)(WSZ / 256), blk, 0, stream>>>(Wq, wqkvb, WSZ);
  cast_bf<<<(int)(WSZ / 256), blk, 0, stream>>>(Wk, wqkvb + WSZ, WSZ);
  cast_bf<<<(int)(WSZ / 256), blk, 0, stream>>>(Wv, wqkvb + 2 * WSZ, WSZ);
  cast_bf<<<(int)(WSZ / 256), blk, 0, stream>>>(Wp, wpb, WSZ);
  cast_split<<<(int)(WSZ / 256), blk, 0, stream>>>(Wo, woh, wol, WSZ);

  // Q,K,V = x@{Wq,Wk,Wv}^T + {bq,bk,bv}   (one z=3 launch, 1536 blocks)
  mfma_gemm_bias<<<dim3(8, 64, 3), blk, 0, stream>>>(
      xbf, wqkvb, bq, bk, bv, Qbf,
      D_MODEL, D_MODEL, 0, WSZ, TD);
  // pf = [Q;K]@Wp^T + bp  (16384 contiguous rows, 1024 blocks)
  mfma_gemm_bias<<<dim3(8, 128, 1), blk, 0, stream>>>(
      Qbf, wpb, bp, bp, bp, pfQ,
      D_MODEL, D_MODEL, 0, 0, 0);
  phase_norm_bf<<<(int)(2 * NROW * N_HALF / 256), blk, 0, stream>>>(pfQ, 2 * NROW);
  zero_stats<<<(int)((2 * NROW + 255) / 256), blk, 0, stream>>>(ssum, (int)(2 * NROW));

  // fused: scores + sync + chaotic -> Cc (fp32), + row stats
  chaotic_fused<<<dim3(16, 16, N_BATCH), blk, 0, stream>>>(
      Qbf, Kbf, pfQ, pfK, Cc, ssum, ssq, bifp, pcp);
  // VWt[b][d][s] = split(Wo) @ V_b^T   (overlays pfQ/pfK, dead after chaotic)
  gemm_asplit<<<dim3(16, 8, N_BATCH), blk, 0, stream>>>(
      woh, wol, Vbf, vwh, vwl,
      S_LEN, D_MODEL, sQ, sQ);
  // softmax (fp32 in, bf16 attn out; overlays Q/K)
  softmax_bf<<<dim3(S_LEN, N_BATCH), blk, 0, stream>>>(Cc, attn);
  // out = attn @ (VWth+VWtl)^T + bo   (fp32 out)
  gemm_bsplit<<<dim3(8, 16, N_BATCH), blk, 0, stream>>>(
      attn, vwh, vwl, bo, out,
      D_MODEL, S_LEN, sS, sQ, sQ);
  // sync_loss
  syncloss_kernel<<<1, 1024, 0, stream>>>(ssum, ssq, out + TD);
}

// Round 8
// 534.215 us; speedup vs baseline: 1.0469x; 1.0469x over previous
//
#include <hip/hip_runtime.h>
#include <hip/hip_bf16.h>
#include <math.h>

#define S_LEN 2048
#define D_MODEL 1024
#define N_BATCH 4
#define N_HALF 512

typedef unsigned short u16;
typedef __attribute__((ext_vector_type(8))) short bf16x8;
typedef __attribute__((ext_vector_type(4))) float f32x4;

// ---------- helpers ----------
__device__ inline u16 f2bf(float v) {
  __hip_bfloat16 h = __float2bfloat16(v);   // RNE
  return *reinterpret_cast<u16*>(&h);
}
__device__ inline float bf2f(u16 u) {
  __hip_bfloat16 h = *reinterpret_cast<__hip_bfloat16*>(&u);
  return __bfloat162float(h);
}
// async global->LDS, 16B per lane; LDS dest is wave-uniform base + lane*16
__device__ inline void gl2lds16(const void* g, void* l) {
  __builtin_amdgcn_global_load_lds(
      (const __attribute__((address_space(1))) unsigned int*)g,
      (__attribute__((address_space(3))) unsigned int*)l, 16, 0, 0);
}
// tanh via v_exp_f32; exact at 0, saturates correctly at +/-inf (no NaN)
__device__ inline float fast_tanh(float x) {
  float e = __expf(2.0f * x);
  return 1.0f - 2.0f / (e + 1.0f);
}

// ---------- casts ----------
__global__ __launch_bounds__(256)
void cast_bf4(const float* __restrict__ src, u16* __restrict__ dst, long long n4) {
  long long i = (long long)blockIdx.x * 256 + threadIdx.x;
  if (i >= n4) return;
  float4 v = ((const float4*)src)[i];
  ushort4 o;
  o.x = f2bf(v.x); o.y = f2bf(v.y); o.z = f2bf(v.z); o.w = f2bf(v.w);
  ((ushort4*)dst)[i] = o;
}
__global__ __launch_bounds__(256)
void cast_split(const float* __restrict__ src, u16* __restrict__ hi,
                u16* __restrict__ lo, long long n) {
  long long i = (long long)blockIdx.x * 256 + threadIdx.x;
  if (i < n) {
    float v = src[i];
    u16 h = f2bf(v);
    hi[i] = h;
    lo[i] = f2bf(v - bf2f(h));
  }
}
// transpose + split: dst[i][j] = split(src[j][i]), 1024x1024
__global__ __launch_bounds__(256)
void transpose_split(const float* __restrict__ src, u16* __restrict__ hi,
                     u16* __restrict__ lo) {
  __shared__ float t[32][33];
  const int bx = blockIdx.x * 32;   // i-base (src col, dst row)
  const int by = blockIdx.y * 32;   // j-base (src row, dst col)
  const int c = threadIdx.x & 31;
  const int r0 = (threadIdx.x >> 5) * 4;
#pragma unroll
  for (int r = 0; r < 4; r++)
    t[r0 + r][c] = src[(long long)(by + r0 + r) * D_MODEL + bx + c];
  __syncthreads();
#pragma unroll
  for (int r = 0; r < 4; r++) {
    float v = t[c][r0 + r];
    long long idx = (long long)(bx + r0 + r) * D_MODEL + by + c;
    u16 h = f2bf(v);
    hi[idx] = h;
    lo[idx] = f2bf(v - bf2f(h));
  }
}
__global__ __launch_bounds__(256)
void zero_stats(float* __restrict__ p, int n) {
  int i = blockIdx.x * 256 + threadIdx.x;
  if (i < n) p[i] = 0.f;
}
// w2b[d] = sum_j Wo[d][j] * bv[j]   (one block per d)
__global__ __launch_bounds__(256)
void w2_bias(const float* __restrict__ Wo, const float* __restrict__ bv,
             float* __restrict__ w2b) {
  const int d = blockIdx.x;
  const int tid = threadIdx.x;
  float acc = 0.f;
  for (int j = tid; j < D_MODEL; j += 256)
    acc += Wo[(long long)d * D_MODEL + j] * bv[j];
#pragma unroll
  for (int m = 1; m < 64; m <<= 1) acc += __shfl_xor(acc, m);
  __shared__ float red[4];
  if ((tid & 63) == 0) red[tid >> 6] = acc;
  __syncthreads();
  if (tid == 0) w2b[d] = red[0] + red[1] + red[2] + red[3];
}

// ============================================================
// Fused Q+K projection: dual-acc NT GEMM sharing the A (=x) staging.
//   acc1 = x@Wq^T, acc2 = x@Wk^T; bf16 out + bias.
// 128x128 tile, 3 LDS tiles (x, Wq, Wk), 32 MFMA / K-iter.
// ============================================================
__global__ __launch_bounds__(256, 2)
void qk_fused(const u16* __restrict__ X, const u16* __restrict__ Wq,
              const u16* __restrict__ Wk,
              const float* __restrict__ bq, const float* __restrict__ bk,
              u16* __restrict__ Qo, u16* __restrict__ Ko) {
  __shared__ u16 Xs[128 * 32];
  __shared__ u16 Qs[128 * 32];
  __shared__ u16 Ks[128 * 32];
  const int tid  = threadIdx.x;
  const int wave = tid >> 6;
  const int lane = tid & 63;
  const int quad = lane >> 4;
  const int tc   = lane & 15;
  const int bm = blockIdx.y * 128;
  const int bn = blockIdx.x * 128;
  const int wm = (wave & 1) * 64;
  const int wn = (wave >> 1) * 64;

  f32x4 acc1[4][4], acc2[4][4];
#pragma unroll
  for (int i = 0; i < 4; i++)
#pragma unroll
    for (int j = 0; j < 4; j++) {
      acc1[i][j] = (f32x4){0.f, 0.f, 0.f, 0.f};
      acc2[i][j] = (f32x4){0.f, 0.f, 0.f, 0.f};
    }

  const int srow = wave * 32 + (lane >> 2);
  const int scol = (lane & 3) * 8;
  const u16* gx = X  + (long long)(bm + srow) * D_MODEL + scol;
  const u16* gq = Wq + (long long)(bn + srow) * D_MODEL + scol;
  const u16* gk = Wk + (long long)(bn + srow) * D_MODEL + scol;
  const int wb = (wave * 32) * 32;
  const long long r16 = 16LL * D_MODEL;

  for (int k0 = 0; k0 < D_MODEL; k0 += 32) {
    gl2lds16(gx,       Xs + wb);
    gl2lds16(gx + r16, Xs + wb + 512);
    gl2lds16(gq,       Qs + wb);
    gl2lds16(gq + r16, Qs + wb + 512);
    gl2lds16(gk,       Ks + wb);
    gl2lds16(gk + r16, Ks + wb + 512);
    gx += 32; gq += 32; gk += 32;
    __syncthreads();
    bf16x8 af[4], bq4[4], bk4[4];
#pragma unroll
    for (int i = 0; i < 4; i++)
      af[i] = *(const bf16x8*)(Xs + (wm + i * 16 + tc) * 32 + quad * 8);
#pragma unroll
    for (int j = 0; j < 4; j++) {
      int o = (wn + j * 16 + tc) * 32 + quad * 8;
      bq4[j] = *(const bf16x8*)(Qs + o);
      bk4[j] = *(const bf16x8*)(Ks + o);
    }
#pragma unroll
    for (int i = 0; i < 4; i++)
#pragma unroll
      for (int j = 0; j < 4; j++) {
        acc1[i][j] = __builtin_amdgcn_mfma_f32_16x16x32_bf16(af[i], bq4[j], acc1[i][j], 0, 0, 0);
        acc2[i][j] = __builtin_amdgcn_mfma_f32_16x16x32_bf16(af[i], bk4[j], acc2[i][j], 0, 0, 0);
      }
    __syncthreads();
  }

#pragma unroll
  for (int i = 0; i < 4; i++) {
    const int row0 = bm + wm + i * 16 + quad * 4;
#pragma unroll
    for (int j = 0; j < 4; j++) {
      const int col = bn + wn + j * 16 + tc;
#pragma unroll
      for (int r = 0; r < 4; r++) {
        long long idx = (long long)(row0 + r) * D_MODEL + col;
        Qo[idx] = f2bf(acc1[i][j][r] + bq[col]);
        Ko[idx] = f2bf(acc2[i][j][r] + bk[col]);
      }
    }
  }
}

// ============================================================
// Fused pfQ+pfK projection: dual-acc NT GEMM sharing the B (=Wp) staging.
//   acc1 = Q@Wp^T, acc2 = K@Wp^T (K rows = Q rows + TD); bf16 out + bp.
// ============================================================
__global__ __launch_bounds__(256, 2)
void pf_fused(const u16* __restrict__ Qb, const u16* __restrict__ Wp,
              const float* __restrict__ bp,
              u16* __restrict__ pfQ, u16* __restrict__ pfK,
              long long TDo) {
  __shared__ u16 Qs[128 * 32];
  __shared__ u16 Ks[128 * 32];
  __shared__ u16 Ws[128 * 32];
  const int tid  = threadIdx.x;
  const int wave = tid >> 6;
  const int lane = tid & 63;
  const int quad = lane >> 4;
  const int tc   = lane & 15;
  const int bm = blockIdx.y * 128;
  const int bn = blockIdx.x * 128;
  const int wm = (wave & 1) * 64;
  const int wn = (wave >> 1) * 64;

  f32x4 acc1[4][4], acc2[4][4];
#pragma unroll
  for (int i = 0; i < 4; i++)
#pragma unroll
    for (int j = 0; j < 4; j++) {
      acc1[i][j] = (f32x4){0.f, 0.f, 0.f, 0.f};
      acc2[i][j] = (f32x4){0.f, 0.f, 0.f, 0.f};
    }

  const int srow = wave * 32 + (lane >> 2);
  const int scol = (lane & 3) * 8;
  const u16* gq = Qb + (long long)(bm + srow) * D_MODEL + scol;
  const u16* gk = gq + TDo;
  const u16* gw = Wp + (long long)(bn + srow) * D_MODEL + scol;
  const int wb = (wave * 32) * 32;
  const long long r16 = 16LL * D_MODEL;

  for (int k0 = 0; k0 < D_MODEL; k0 += 32) {
    gl2lds16(gq,       Qs + wb);
    gl2lds16(gq + r16, Qs + wb + 512);
    gl2lds16(gk,       Ks + wb);
    gl2lds16(gk + r16, Ks + wb + 512);
    gl2lds16(gw,       Ws + wb);
    gl2lds16(gw + r16, Ws + wb + 512);
    gq += 32; gk += 32; gw += 32;
    __syncthreads();
    bf16x8 aq[4], ak[4], bw[4];
#pragma unroll
    for (int i = 0; i < 4; i++) {
      int o = (wm + i * 16 + tc) * 32 + quad * 8;
      aq[i] = *(const bf16x8*)(Qs + o);
      ak[i] = *(const bf16x8*)(Ks + o);
    }
#pragma unroll
    for (int j = 0; j < 4; j++)
      bw[j] = *(const bf16x8*)(Ws + (wn + j * 16 + tc) * 32 + quad * 8);
#pragma unroll
    for (int i = 0; i < 4; i++)
#pragma unroll
      for (int j = 0; j < 4; j++) {
        acc1[i][j] = __builtin_amdgcn_mfma_f32_16x16x32_bf16(aq[i], bw[j], acc1[i][j], 0, 0, 0);
        acc2[i][j] = __builtin_amdgcn_mfma_f32_16x16x32_bf16(ak[i], bw[j], acc2[i][j], 0, 0, 0);
      }
    __syncthreads();
  }

#pragma unroll
  for (int i = 0; i < 4; i++) {
    const int row0 = bm + wm + i * 16 + quad * 4;
#pragma unroll
    for (int j = 0; j < 4; j++) {
      const int col = bn + wn + j * 16 + tc;
#pragma unroll
      for (int r = 0; r < 4; r++) {
        long long idx = (long long)(row0 + r) * D_MODEL + col;
        float b = bp[col];
        pfQ[idx] = f2bf(acc1[i][j][r] + b);
        pfK[idx] = f2bf(acc2[i][j][r] + b);
      }
    }
  }
}

// ============================================================
// Split-precision GEMM: C = (Ah+Al)(Bh+Bl)^T (+bias), fp32 out.
// 3 MFMAs per frag step (drop Al*Bl). Used for W2 = split(Wo)@split(Wv^T)^T.
// ============================================================
__global__ __launch_bounds__(256)
void mfma_gemm_out3(const u16* __restrict__ Ah, const u16* __restrict__ Al,
                    const u16* __restrict__ Bh, const u16* __restrict__ Bl,
                    const float* __restrict__ bias, float* __restrict__ C,
                    int N, int K) {
  __shared__ u16 Ash[128 * 32];
  __shared__ u16 Asl[128 * 32];
  __shared__ u16 Bsh[128 * 32];
  __shared__ u16 Bsl[128 * 32];
  const int tid  = threadIdx.x;
  const int wave = tid >> 6;
  const int lane = tid & 63;
  const int quad = lane >> 4;
  const int tc   = lane & 15;
  const int bm = blockIdx.y * 128;
  const int bn = blockIdx.x * 128;
  const int wm = (wave & 1) * 64;
  const int wn = (wave >> 1) * 64;

  f32x4 acc[4][4];
#pragma unroll
  for (int i = 0; i < 4; i++)
#pragma unroll
    for (int j = 0; j < 4; j++) acc[i][j] = (f32x4){0.f, 0.f, 0.f, 0.f};

  const int srow = wave * 32 + (lane >> 2);
  const int scol = (lane & 3) * 8;
  long long aoff = (long long)(bm + srow) * K + scol;
  long long boff = (long long)(bn + srow) * K + scol;
  const u16 *gah = Ah + aoff, *gal = Al + aoff;
  const u16 *gbh = Bh + boff, *gbl = Bl + boff;
  const int wbase = (wave * 32) * 32;
  const long long r16K = 16LL * K;

  for (int k0 = 0; k0 < K; k0 += 32) {
    gl2lds16(gah,        Ash + wbase);
    gl2lds16(gah + r16K, Ash + wbase + 512);
    gl2lds16(gal,        Asl + wbase);
    gl2lds16(gal + r16K, Asl + wbase + 512);
    gl2lds16(gbh,        Bsh + wbase);
    gl2lds16(gbh + r16K, Bsh + wbase + 512);
    gl2lds16(gbl,        Bsl + wbase);
    gl2lds16(gbl + r16K, Bsl + wbase + 512);
    gah += 32; gal += 32; gbh += 32; gbl += 32;
    __syncthreads();
    bf16x8 ah[4], al[4], bh[4], bl[4];
#pragma unroll
    for (int i = 0; i < 4; i++) {
      int o = (wm + i * 16 + tc) * 32 + quad * 8;
      ah[i] = *(const bf16x8*)(Ash + o);
      al[i] = *(const bf16x8*)(Asl + o);
    }
#pragma unroll
    for (int j = 0; j < 4; j++) {
      int o = (wn + j * 16 + tc) * 32 + quad * 8;
      bh[j] = *(const bf16x8*)(Bsh + o);
      bl[j] = *(const bf16x8*)(Bsl + o);
    }
#pragma unroll
    for (int i = 0; i < 4; i++)
#pragma unroll
      for (int j = 0; j < 4; j++) {
        acc[i][j] = __builtin_amdgcn_mfma_f32_16x16x32_bf16(ah[i], bh[j], acc[i][j], 0, 0, 0);
        acc[i][j] = __builtin_amdgcn_mfma_f32_16x16x32_bf16(ah[i], bl[j], acc[i][j], 0, 0, 0);
        acc[i][j] = __builtin_amdgcn_mfma_f32_16x16x32_bf16(al[i], bh[j], acc[i][j], 0, 0, 0);
      }
    __syncthreads();
  }
#pragma unroll
  for (int i = 0; i < 4; i++) {
    const int row0 = bm + wm + i * 16 + quad * 4;
#pragma unroll
    for (int j = 0; j < 4; j++) {
      const int col = bn + wn + j * 16 + tc;
      float b = bias ? bias[col] : 0.f;
#pragma unroll
      for (int r = 0; r < 4; r++)
        C[(long long)(row0 + r) * N + col] = acc[i][j][r] + b;
    }
  }
}

// ============================================================
// VWt[b][d][s] = (W2h+W2l) @ x_b^T + w2b[d], hi/lo bf16 out.
// A-split shared-B staging: 3 LDS tiles, 32 MFMA / iter, single acc.
// ============================================================
__global__ __launch_bounds__(256)
void vwt_kernel(const u16* __restrict__ W2h, const u16* __restrict__ W2l,
                const u16* __restrict__ X, const float* __restrict__ w2b,
                u16* __restrict__ Ch, u16* __restrict__ Cl,
                long long sB, long long sC) {
  __shared__ u16 Ah[128 * 32];
  __shared__ u16 Al[128 * 32];
  __shared__ u16 Bs[128 * 32];
  const int tid  = threadIdx.x;
  const int wave = tid >> 6;
  const int lane = tid & 63;
  const int quad = lane >> 4;
  const int tc   = lane & 15;
  const int bm = blockIdx.y * 128;   // d
  const int bn = blockIdx.x * 128;   // s
  const long long z = blockIdx.z;
  const int wm = (wave & 1) * 64;
  const int wn = (wave >> 1) * 64;

  f32x4 acc[4][4];
#pragma unroll
  for (int i = 0; i < 4; i++)
#pragma unroll
    for (int j = 0; j < 4; j++) acc[i][j] = (f32x4){0.f, 0.f, 0.f, 0.f};

  const int srow = wave * 32 + (lane >> 2);
  const int scol = (lane & 3) * 8;
  const long long aoff = (long long)(bm + srow) * D_MODEL + scol;
  const u16* gah = W2h + aoff;
  const u16* gal = W2l + aoff;
  const u16* gb  = X + z * sB + (long long)(bn + srow) * D_MODEL + scol;
  const int wb = (wave * 32) * 32;
  const long long r16 = 16LL * D_MODEL;

  for (int k0 = 0; k0 < D_MODEL; k0 += 32) {
    gl2lds16(gah,       Ah + wb);
    gl2lds16(gah + r16, Ah + wb + 512);
    gl2lds16(gal,       Al + wb);
    gl2lds16(gal + r16, Al + wb + 512);
    gl2lds16(gb,        Bs + wb);
    gl2lds16(gb + r16,  Bs + wb + 512);
    gah += 32; gal += 32; gb += 32;
    __syncthreads();
    bf16x8 ah4[4], al4[4], bx[4];
#pragma unroll
    for (int i = 0; i < 4; i++) {
      int o = (wm + i * 16 + tc) * 32 + quad * 8;
      ah4[i] = *(const bf16x8*)(Ah + o);
      al4[i] = *(const bf16x8*)(Al + o);
    }
#pragma unroll
    for (int j = 0; j < 4; j++)
      bx[j] = *(const bf16x8*)(Bs + (wn + j * 16 + tc) * 32 + quad * 8);
#pragma unroll
    for (int i = 0; i < 4; i++)
#pragma unroll
      for (int j = 0; j < 4; j++) {
        acc[i][j] = __builtin_amdgcn_mfma_f32_16x16x32_bf16(ah4[i], bx[j], acc[i][j], 0, 0, 0);
        acc[i][j] = __builtin_amdgcn_mfma_f32_16x16x32_bf16(al4[i], bx[j], acc[i][j], 0, 0, 0);
      }
    __syncthreads();
  }

  u16* Chz = Ch + z * sC;
  u16* Clz = Cl + z * sC;
#pragma unroll
  for (int i = 0; i < 4; i++) {
    const int row0 = bm + wm + i * 16 + quad * 4;
#pragma unroll
    for (int j = 0; j < 4; j++) {
      const int col = bn + wn + j * 16 + tc;
#pragma unroll
      for (int r = 0; r < 4; r++) {
        float v = acc[i][j][r] + w2b[row0 + r];
        long long idx = (long long)(row0 + r) * S_LEN + col;
        u16 h = f2bf(v);
        Chz[idx] = h;
        Clz[idx] = f2bf(v - bf2f(h));
      }
    }
  }
}

// ============================================================
// B-split GEMM (out): C = A @ (Bh+Bl)^T + bias[col], fp32 out. (round-7 body)
// ============================================================
__global__ __launch_bounds__(256)
void gemm_bsplit(const u16* __restrict__ A,
                 const u16* __restrict__ Bh, const u16* __restrict__ Bl,
                 const float* __restrict__ bias, float* __restrict__ C,
                 int N, int K, long long sA, long long sB, long long sC) {
  __shared__ u16 As[128 * 32];
  __shared__ u16 Bsh[128 * 32];
  __shared__ u16 Bsl[128 * 32];
  const int tid  = threadIdx.x;
  const int wave = tid >> 6;
  const int lane = tid & 63;
  const int quad = lane >> 4;
  const int tc   = lane & 15;
  const int bm = blockIdx.y * 128;
  const int bn = blockIdx.x * 128;
  const long long z = blockIdx.z;
  const int wm = (wave & 1) * 64;
  const int wn = (wave >> 1) * 64;

  f32x4 acc[4][4];
#pragma unroll
  for (int i = 0; i < 4; i++)
#pragma unroll
    for (int j = 0; j < 4; j++) acc[i][j] = (f32x4){0.f, 0.f, 0.f, 0.f};

  const int srow = wave * 32 + (lane >> 2);
  const int scol = (lane & 3) * 8;
  const long long boff = (long long)(bn + srow) * K + scol;
  const u16* ga  = A + z * sA + (long long)(bm + srow) * K + scol;
  const u16* gbh = Bh + z * sB + boff;
  const u16* gbl = Bl + z * sB + boff;
  const int wb = (wave * 32) * 32;
  const long long r16K = 16LL * K;

  for (int k0 = 0; k0 < K; k0 += 32) {
    gl2lds16(ga,         As + wb);
    gl2lds16(ga + r16K,  As + wb + 512);
    gl2lds16(gbh,        Bsh + wb);
    gl2lds16(gbh + r16K, Bsh + wb + 512);
    gl2lds16(gbl,        Bsl + wb);
    gl2lds16(gbl + r16K, Bsl + wb + 512);
    ga += 32; gbh += 32; gbl += 32;
    __syncthreads();
    bf16x8 af[4], bh[4], bl[4];
#pragma unroll
    for (int i = 0; i < 4; i++)
      af[i] = *(const bf16x8*)(As + (wm + i * 16 + tc) * 32 + quad * 8);
#pragma unroll
    for (int j = 0; j < 4; j++) {
      int o = (wn + j * 16 + tc) * 32 + quad * 8;
      bh[j] = *(const bf16x8*)(Bsh + o);
      bl[j] = *(const bf16x8*)(Bsl + o);
    }
#pragma unroll
    for (int i = 0; i < 4; i++)
#pragma unroll
      for (int j = 0; j < 4; j++) {
        acc[i][j] = __builtin_amdgcn_mfma_f32_16x16x32_bf16(af[i], bh[j], acc[i][j], 0, 0, 0);
        acc[i][j] = __builtin_amdgcn_mfma_f32_16x16x32_bf16(af[i], bl[j], acc[i][j], 0, 0, 0);
      }
    __syncthreads();
  }

  float* Cz = C + z * sC;
#pragma unroll
  for (int i = 0; i < 4; i++) {
    const int row0 = bm + wm + i * 16 + quad * 4;
#pragma unroll
    for (int j = 0; j < 4; j++) {
      const int col = bn + wn + j * 16 + tc;
#pragma unroll
      for (int r = 0; r < 4; r++)
        Cz[(long long)(row0 + r) * N + col] = acc[i][j][r] + bias[col];
    }
  }
}

// ============================================================
// Fused chaotic kernel (validated round-6 body, unchanged).
// ============================================================
__global__ __launch_bounds__(256, 2)
void chaotic_fused(const u16* __restrict__ Q, const u16* __restrict__ Kt,
                   const u16* __restrict__ Uq, const u16* __restrict__ Uk,
                   float* __restrict__ Cc,
                   float* __restrict__ ssum, float* __restrict__ ssq,
                   const float* __restrict__ bifp, const float* __restrict__ pcp) {
  __shared__ u16 Qs[128 * 32];
  __shared__ u16 Ks[128 * 32];
  __shared__ u16 Us[128 * 32];
  __shared__ u16 Ws[128 * 32];
  const int tid  = threadIdx.x;
  const int wave = tid >> 6;
  const int lane = tid & 63;
  const int quad = lane >> 4;
  const int tc   = lane & 15;
  const int bm = blockIdx.y * 128;
  const int bn = blockIdx.x * 128;
  const long long z = blockIdx.z;
  const long long sQ = (long long)S_LEN * D_MODEL;
  const int wm = (wave & 1) * 64;
  const int wn = (wave >> 1) * 64;

  f32x4 acc1[4][4], acc2[4][4];
#pragma unroll
  for (int i = 0; i < 4; i++)
#pragma unroll
    for (int j = 0; j < 4; j++) {
      acc1[i][j] = (f32x4){0.f, 0.f, 0.f, 0.f};
      acc2[i][j] = (f32x4){0.f, 0.f, 0.f, 0.f};
    }

  const int srow = wave * 32 + (lane >> 2);
  const int scol = (lane & 3) * 8;
  const long long aoff = (long long)(bm + srow) * D_MODEL + scol;
  const long long boff = (long long)(bn + srow) * D_MODEL + scol;
  const u16* gq = Q  + z * sQ + aoff;
  const u16* gk = Kt + z * sQ + boff;
  const u16* gu = Uq + z * sQ + aoff;
  const u16* gw = Uk + z * sQ + boff;
  const int wb = (wave * 32) * 32;
  const long long r16 = 16LL * D_MODEL;

  for (int k0 = 0; k0 < D_MODEL; k0 += 32) {
    gl2lds16(gq,       Qs + wb);
    gl2lds16(gq + r16, Qs + wb + 512);
    gl2lds16(gk,       Ks + wb);
    gl2lds16(gk + r16, Ks + wb + 512);
    gl2lds16(gu,       Us + wb);
    gl2lds16(gu + r16, Us + wb + 512);
    gl2lds16(gw,       Ws + wb);
    gl2lds16(gw + r16, Ws + wb + 512);
    gq += 32; gk += 32; gu += 32; gw += 32;
    __syncthreads();
    {
      bf16x8 af[4], bg[4];
#pragma unroll
      for (int i = 0; i < 4; i++)
        af[i] = *(const bf16x8*)(Qs + (wm + i * 16 + tc) * 32 + quad * 8);
#pragma unroll
      for (int j = 0; j < 4; j++)
        bg[j] = *(const bf16x8*)(Ks + (wn + j * 16 + tc) * 32 + quad * 8);
#pragma unroll
      for (int i = 0; i < 4; i++)
#pragma unroll
        for (int j = 0; j < 4; j++)
          acc1[i][j] = __builtin_amdgcn_mfma_f32_16x16x32_bf16(af[i], bg[j], acc1[i][j], 0, 0, 0);
    }
    {
      bf16x8 cf[4], dg[4];
#pragma unroll
      for (int i = 0; i < 4; i++)
        cf[i] = *(const bf16x8*)(Us + (wm + i * 16 + tc) * 32 + quad * 8);
#pragma unroll
      for (int j = 0; j < 4; j++)
        dg[j] = *(const bf16x8*)(Ws + (wn + j * 16 + tc) * 32 + quad * 8);
#pragma unroll
      for (int i = 0; i < 4; i++)
#pragma unroll
        for (int j = 0; j < 4; j++)
          acc2[i][j] = __builtin_amdgcn_mfma_f32_16x16x32_bf16(cf[i], dg[j], acc2[i][j], 0, 0, 0);
    }
    __syncthreads();
  }

  const float bif = *bifp;
  const float pc  = *pcp;
  float rsum[4][4], rsq[4][4];
#pragma unroll
  for (int i = 0; i < 4; i++)
#pragma unroll
    for (int r = 0; r < 4; r++) { rsum[i][r] = 0.f; rsq[i][r] = 0.f; }

  float* C = Cc + z * (long long)S_LEN * S_LEN;
#pragma unroll
  for (int i = 0; i < 4; i++) {
    const int row0 = bm + wm + i * 16 + quad * 4;
#pragma unroll
    for (int j = 0; j < 4; j++) {
      const int col = bn + wn + j * 16 + tc;
#pragma unroll
      for (int r = 0; r < 4; r++) {
        float sc = acc1[i][j][r] * 0.03125f;          // / sqrt(1024)
        float sy = acc2[i][j][r] * (1.0f / 512.0f);   // / HALF
        float t  = fast_tanh(sc);
        C[(long long)(row0 + r) * S_LEN + col] = sc + pc * sy + bif * t * (1.0f - t);
        rsum[i][r] += sy;
        rsq[i][r]  += sy * sy;
      }
    }
  }
#pragma unroll
  for (int m = 1; m < 16; m <<= 1) {
#pragma unroll
    for (int i = 0; i < 4; i++)
#pragma unroll
      for (int r = 0; r < 4; r++) {
        rsum[i][r] += __shfl_xor(rsum[i][r], m);
        rsq[i][r]  += __shfl_xor(rsq[i][r], m);
      }
  }
  if (tc == 0) {
#pragma unroll
    for (int i = 0; i < 4; i++)
#pragma unroll
      for (int r = 0; r < 4; r++) {
        long long rr = z * S_LEN + bm + wm + i * 16 + quad * 4 + r;
        atomicAdd(&ssum[rr], rsum[i][r]);
        atomicAdd(&ssq[rr],  rsq[i][r]);
      }
  }
}

// ============================================================
// Phase normalize in place on dense bf16 pf rows (stride 1024)
// ============================================================
__global__ __launch_bounds__(256)
void phase_norm_bf(u16* __restrict__ U, long long n_rows) {
  long long idx = (long long)blockIdx.x * 256 + threadIdx.x;
  if (idx >= n_rows * N_HALF) return;
  long long row = idx >> 9;
  int j = (int)(idx & (N_HALF - 1));
  u16* p = U + row * D_MODEL;
  float re = bf2f(p[j]), im = bf2f(p[j + N_HALF]);
  float n2 = re * re + im * im;
  float cr = 1.f, sr = 0.f;
  if (n2 > 0.f) {
    float inv = 1.0f / sqrtf(n2);
    cr = re * inv; sr = im * inv;
  }
  p[j] = f2bf(cr); p[j + N_HALF] = f2bf(sr);
}

// ============================================================
// Row softmax: fp32 in (chaotic), bf16 out (attn). 1 block / row.
// ============================================================
__global__ __launch_bounds__(256)
void softmax_bf(const float* __restrict__ Cc, u16* __restrict__ P) {
  const long long row = (long long)blockIdx.y * S_LEN + blockIdx.x;
  const float* p = Cc + row * S_LEN;
  u16* q = P + row * S_LEN;
  const int tid = threadIdx.x;
  float v[8];
  float m = -3.402823466e+38f;
#pragma unroll
  for (int i = 0; i < 8; i++) { v[i] = p[tid + i * 256]; m = fmaxf(m, v[i]); }
#pragma unroll
  for (int mask = 1; mask < 64; mask <<= 1) m = fmaxf(m, __shfl_xor(m, mask));
  __shared__ float red[8];
  if ((tid & 63) == 0) red[tid >> 6] = m;
  __syncthreads();
  m = fmaxf(fmaxf(red[0], red[1]), fmaxf(red[2], red[3]));
  float s = 0.f;
#pragma unroll
  for (int i = 0; i < 8; i++) { v[i] = __expf(v[i] - m); s += v[i]; }
#pragma unroll
  for (int mask = 1; mask < 64; mask <<= 1) s += __shfl_xor(s, mask);
  __syncthreads();
  if ((tid & 63) == 0) red[4 + (tid >> 6)] = s;
  __syncthreads();
  s = red[4] + red[5] + red[6] + red[7];
  float inv = 1.0f / s;
#pragma unroll
  for (int i = 0; i < 8; i++) q[tid + i * 256] = f2bf(v[i] * inv);
}

// ============================================================
// sync_loss
// ============================================================
__global__ __launch_bounds__(1024)
void syncloss_kernel(const float* __restrict__ ssum, const float* __restrict__ ssq,
                     float* __restrict__ out) {
  const int tid = threadIdx.x;
  float acc = 0.f;
  for (int r = tid; r < N_BATCH * S_LEN; r += 1024) {
    float su = ssum[r], sq = ssq[r];
    acc += (sq - su * su * (1.0f / 2048.0f)) * (1.0f / 2047.0f);
  }
#pragma unroll
  for (int mask = 1; mask < 64; mask <<= 1) acc += __shfl_xor(acc, mask);
  __shared__ float red[16];
  if ((tid & 63) == 0) red[tid >> 6] = acc;
  __syncthreads();
  if (tid == 0) {
    float t = 0.f;
#pragma unroll
    for (int k = 0; k < 16; k++) t += red[k];
    out[0] = 0.01f * (t / (float)(N_BATCH * S_LEN));
  }
}

extern "C" void kernel_launch(void* const* d_in, const int* in_sizes, int n_in,
                              void* d_out, int out_size, void* d_ws, size_t ws_size,
                              hipStream_t stream) {
  const float* x    = (const float*)d_in[0];
  const float* Wq   = (const float*)d_in[1];
  const float* bq   = (const float*)d_in[2];
  const float* Wk   = (const float*)d_in[3];
  const float* bk   = (const float*)d_in[4];
  const float* Wv   = (const float*)d_in[5];
  const float* bv   = (const float*)d_in[6];
  const float* Wp   = (const float*)d_in[7];
  const float* bp   = (const float*)d_in[8];
  const float* Wo   = (const float*)d_in[9];
  const float* bo   = (const float*)d_in[10];
  const float* bifp = (const float*)d_in[11];
  const float* pcp  = (const float*)d_in[12];
  float* out = (float*)d_out;

  const long long NROW = (long long)N_BATCH * S_LEN;   // 8192
  const long long TD   = NROW * D_MODEL;               // 8,388,608
  const long long WSZ  = (long long)D_MODEL * D_MODEL; // 1,048,576

  // workspace layout (~171 MB)
  u16* xbf   = (u16*)d_ws;          // TD
  u16* wqb   = xbf + TD;            // WSZ
  u16* wkb   = wqb + WSZ;           // WSZ
  u16* wpb   = wkb + WSZ;           // WSZ
  u16* woh   = wpb + WSZ;           // WSZ (Wo hi/lo)
  u16* wol   = woh + WSZ;
  u16* wvth  = wol + WSZ;           // WSZ (Wv^T hi/lo)
  u16* wvtl  = wvth + WSZ;
  u16* w2h   = wvtl + WSZ;          // WSZ (W2 hi/lo)
  u16* w2l   = w2h + WSZ;
  float* W2f = (float*)(w2l + WSZ); // WSZ floats (4 MB)
  float* w2b = W2f + WSZ;           // 1024 floats
  u16* Qbf   = (u16*)(w2b + D_MODEL); // TD
  u16* Kbf   = Qbf + TD;            // TD (contiguous)
  u16* pfQ   = Kbf + TD;            // TD
  u16* pfK   = pfQ + TD;            // TD (contiguous)
  float* Cc  = (float*)(pfK + TD);  // B*S*S fp32 (67 MB)
  float* ssum = Cc + (long long)N_BATCH * S_LEN * S_LEN;
  float* ssq  = ssum + NROW;
  u16* attn = Qbf;                  // overlays Q+K after chaotic (2*TD)
  u16* vwh  = pfQ;                  // overlays Uq after chaotic
  u16* vwl  = pfK;                  // overlays Uk after chaotic

  dim3 blk(256);
  const long long sQ = (long long)S_LEN * D_MODEL;   // 2048*1024
  const long long sS = (long long)S_LEN * S_LEN;

  // ---- casts & W2 precompute ----
  cast_bf4<<<(int)(TD / 4 / 256), blk, 0, stream>>>(x, xbf, TD / 4);
  cast_bf4<<<(int)(WSZ / 4 / 256), blk, 0, stream>>>(Wq, wqb, WSZ / 4);
  cast_bf4<<<(int)(WSZ / 4 / 256), blk, 0, stream>>>(Wk, wkb, WSZ / 4);
  cast_bf4<<<(int)(WSZ / 4 / 256), blk, 0, stream>>>(Wp, wpb, WSZ / 4);
  cast_split<<<(int)(WSZ / 256), blk, 0, stream>>>(Wo, woh, wol, WSZ);
  transpose_split<<<dim3(32, 32), blk, 0, stream>>>(Wv, wvth, wvtl);
  // W2 = split(Wo) @ split(Wv^T)^T  (fp32), then split; w2b = Wo @ bv
  mfma_gemm_out3<<<dim3(8, 8, 1), blk, 0, stream>>>(
      woh, wol, wvth, wvtl, nullptr, W2f, D_MODEL, D_MODEL);
  cast_split<<<(int)(WSZ / 256), blk, 0, stream>>>(W2f, w2h, w2l, WSZ);
  w2_bias<<<D_MODEL, blk, 0, stream>>>(Wo, bv, w2b);

  // ---- Q,K fused projection ----
  qk_fused<<<dim3(8, 64), blk, 0, stream>>>(xbf, wqb, wkb, bq, bk, Qbf, Kbf);
  // ---- pfQ,pfK fused projection ----
  pf_fused<<<dim3(8, 64), blk, 0, stream>>>(Qbf, wpb, bp, pfQ, pfK, TD);
  phase_norm_bf<<<(int)(2 * NROW * N_HALF / 256), blk, 0, stream>>>(pfQ, 2 * NROW);
  zero_stats<<<(int)((2 * NROW + 255) / 256), blk, 0, stream>>>(ssum, (int)(2 * NROW));

  // ---- fused scores + sync + chaotic ----
  chaotic_fused<<<dim3(16, 16, N_BATCH), blk, 0, stream>>>(
      Qbf, Kbf, pfQ, pfK, Cc, ssum, ssq, bifp, pcp);
  // ---- VWt = split(W2) @ x_b^T + w2b (overlays pf, dead after chaotic) ----
  vwt_kernel<<<dim3(16, 8, N_BATCH), blk, 0, stream>>>(
      w2h, w2l, xbf, w2b, vwh, vwl, sQ, sQ);
  // ---- softmax (overlays Q/K) ----
  softmax_bf<<<dim3(S_LEN, N_BATCH), blk, 0, stream>>>(Cc, attn);
  // ---- out = attn @ (VWth+VWtl)^T + bo ----
  gemm_bsplit<<<dim3(8, 16, N_BATCH), blk, 0, stream>>>(
      attn, vwh, vwl, bo, out,
      D_MODEL, S_LEN, sS, sQ, sQ);
  // ---- sync_loss ----
  syncloss_kernel<<<1, 1024, 0, stream>>>(ssum, ssq, out + TD);
}